// Round 1
// baseline (1770.807 us; speedup 1.0000x reference)
//
#include <hip/hip_runtime.h>

// GraphSAGE 2-layer, fp32.
// out = SAGE2( relu( SAGE1(x) ) ), SAGE(x) = meanagg(x)@W_l + x@W_r + b
// Restructure layer 2: meanagg(h)@W2_l == meanagg(h@W2_l)  (linearity) -> scatter 64 floats/edge.

__global__ void deg_kernel(const int* __restrict__ dst, float* __restrict__ deg, int E) {
    int e = blockIdx.x * blockDim.x + threadIdx.x;
    if (e < E) atomicAdd(&deg[dst[e]], 1.0f);
}

__global__ void invdeg_kernel(float* __restrict__ deg, int N) {
    int i = blockIdx.x * blockDim.x + threadIdx.x;
    if (i < N) deg[i] = 1.0f / fmaxf(deg[i], 1.0f);
}

// One edge handled by C4 threads; each thread moves 4 consecutive floats.
// scale==nullptr: plain add. scale!=nullptr: contribution scaled by scale[dst].
template<int C4>
__global__ void scatter_add_kernel(const int* __restrict__ src, const int* __restrict__ dst,
                                   const float* __restrict__ feat, float* __restrict__ out,
                                   const float* __restrict__ scale, int E) {
    int t = blockIdx.x * blockDim.x + threadIdx.x;
    int e = t / C4;
    int c = t % C4;
    if (e >= E) return;
    int s = src[e], d = dst[e];
    float4 v = *(const float4*)(feat + (size_t)s * (C4 * 4) + c * 4);
    float sc = scale ? scale[d] : 1.0f;
    float* o = out + (size_t)d * (C4 * 4) + c * 4;
    atomicAdd(o + 0, v.x * sc);
    atomicAdd(o + 1, v.y * sc);
    atomicAdd(o + 2, v.z * sc);
    atomicAdd(o + 3, v.w * sc);
}

// Layer 1: h[n][o] = relu( (inv[n]*agg[n]) @ W1l + x[n] @ W1r + b1 )  (K=256 virtual)
__global__ __launch_bounds__(256) void gemm1_kernel(
    const float* __restrict__ agg, const float* __restrict__ x,
    const float* __restrict__ inv,
    const float* __restrict__ Wl, const float* __restrict__ Wr,
    const float* __restrict__ b, float* __restrict__ h, int N)
{
    __shared__ float At[64][68];    // 64 nodes x 64 k, padded
    __shared__ float Wt[64][132];   // 64 k x 128 out, padded
    const int tid = threadIdx.x;
    const int tx = tid & 15;        // output group: cols tx*8 .. tx*8+7
    const int ty = tid >> 4;        // node group: rows ty*4 .. ty*4+3
    const int nbase = blockIdx.x * 64;

    float acc[4][8];
#pragma unroll
    for (int i = 0; i < 4; ++i)
#pragma unroll
        for (int j = 0; j < 8; ++j) acc[i][j] = 0.f;

    for (int kt = 0; kt < 4; ++kt) {
        const float* Asrc = (kt < 2) ? agg : x;
        const int kcol = (kt & 1) * 64;
        const bool scaled = (kt < 2);
        // stage A: 64 rows x 64 cols = 1024 float4, 4 per thread
#pragma unroll
        for (int i = 0; i < 4; ++i) {
            int f = tid + i * 256;
            int row = f >> 4, c4 = f & 15;
            int g = nbase + row;
            float4 v = make_float4(0.f, 0.f, 0.f, 0.f);
            if (g < N) {
                v = *(const float4*)(Asrc + (size_t)g * 128 + kcol + c4 * 4);
                if (scaled) { float s = inv[g]; v.x *= s; v.y *= s; v.z *= s; v.w *= s; }
            }
            *(float4*)&At[row][c4 * 4] = v;
        }
        // stage W: rows kt*64..+63 of [W1l; W1r] (256x128): 2048 float4, 8 per thread
#pragma unroll
        for (int i = 0; i < 8; ++i) {
            int f = tid + i * 256;
            int row = f >> 5, c4 = f & 31;
            int gk = kt * 64 + row;
            const float* Wsrc = (gk < 128) ? Wl : Wr;
            int wr = gk & 127;
            float4 v = *(const float4*)(Wsrc + wr * 128 + c4 * 4);
            *(float4*)&Wt[row][c4 * 4] = v;
        }
        __syncthreads();
#pragma unroll 8
        for (int kk = 0; kk < 64; ++kk) {
            float a0 = At[ty * 4 + 0][kk];
            float a1 = At[ty * 4 + 1][kk];
            float a2 = At[ty * 4 + 2][kk];
            float a3 = At[ty * 4 + 3][kk];
            float4 w0 = *(const float4*)&Wt[kk][tx * 8];
            float4 w1 = *(const float4*)&Wt[kk][tx * 8 + 4];
            const float wv[8] = {w0.x, w0.y, w0.z, w0.w, w1.x, w1.y, w1.z, w1.w};
#pragma unroll
            for (int j = 0; j < 8; ++j) {
                acc[0][j] += a0 * wv[j];
                acc[1][j] += a1 * wv[j];
                acc[2][j] += a2 * wv[j];
                acc[3][j] += a3 * wv[j];
            }
        }
        __syncthreads();
    }
    float4 b0 = *(const float4*)(b + tx * 8);
    float4 b1v = *(const float4*)(b + tx * 8 + 4);
    const float bv[8] = {b0.x, b0.y, b0.z, b0.w, b1v.x, b1v.y, b1v.z, b1v.w};
#pragma unroll
    for (int i = 0; i < 4; ++i) {
        int g = nbase + ty * 4 + i;
        if (g < N) {
            float o[8];
#pragma unroll
            for (int j = 0; j < 8; ++j) o[j] = fmaxf(acc[i][j] + bv[j], 0.f);
            float* p = h + (size_t)g * 128 + tx * 8;
            *(float4*)p = make_float4(o[0], o[1], o[2], o[3]);
            *(float4*)(p + 4) = make_float4(o[4], o[5], o[6], o[7]);
        }
    }
}

// Layer 2: cols 0..63 -> hl = h@W2l (to be scatter-aggregated);
//          cols 64..127 -> d_out = h@W2r + b2 (self term, scatter adds on top)
__global__ __launch_bounds__(256) void gemm2_kernel(
    const float* __restrict__ hin,
    const float* __restrict__ Wl, const float* __restrict__ Wr,
    const float* __restrict__ b, float* __restrict__ hl,
    float* __restrict__ outp, int N)
{
    __shared__ float At[64][68];
    __shared__ float Wt[64][132];
    const int tid = threadIdx.x;
    const int tx = tid & 15;
    const int ty = tid >> 4;
    const int nbase = blockIdx.x * 64;

    float acc[4][8];
#pragma unroll
    for (int i = 0; i < 4; ++i)
#pragma unroll
        for (int j = 0; j < 8; ++j) acc[i][j] = 0.f;

    for (int kt = 0; kt < 2; ++kt) {
        const int kcol = kt * 64;
#pragma unroll
        for (int i = 0; i < 4; ++i) {
            int f = tid + i * 256;
            int row = f >> 4, c4 = f & 15;
            int g = nbase + row;
            float4 v = make_float4(0.f, 0.f, 0.f, 0.f);
            if (g < N) v = *(const float4*)(hin + (size_t)g * 128 + kcol + c4 * 4);
            *(float4*)&At[row][c4 * 4] = v;
        }
        // W: cols 0..63 from W2l[128][64], cols 64..127 from W2r[128][64]
#pragma unroll
        for (int i = 0; i < 8; ++i) {
            int f = tid + i * 256;
            int row = f >> 5, c4 = f & 31;
            int gk = kt * 64 + row;
            float4 v;
            if (c4 < 16) v = *(const float4*)(Wl + gk * 64 + c4 * 4);
            else         v = *(const float4*)(Wr + gk * 64 + (c4 - 16) * 4);
            *(float4*)&Wt[row][c4 * 4] = v;
        }
        __syncthreads();
#pragma unroll 8
        for (int kk = 0; kk < 64; ++kk) {
            float a0 = At[ty * 4 + 0][kk];
            float a1 = At[ty * 4 + 1][kk];
            float a2 = At[ty * 4 + 2][kk];
            float a3 = At[ty * 4 + 3][kk];
            float4 w0 = *(const float4*)&Wt[kk][tx * 8];
            float4 w1 = *(const float4*)&Wt[kk][tx * 8 + 4];
            const float wv[8] = {w0.x, w0.y, w0.z, w0.w, w1.x, w1.y, w1.z, w1.w};
#pragma unroll
            for (int j = 0; j < 8; ++j) {
                acc[0][j] += a0 * wv[j];
                acc[1][j] += a1 * wv[j];
                acc[2][j] += a2 * wv[j];
                acc[3][j] += a3 * wv[j];
            }
        }
        __syncthreads();
    }
    if (tx < 8) {
#pragma unroll
        for (int i = 0; i < 4; ++i) {
            int g = nbase + ty * 4 + i;
            if (g < N) {
                float* p = hl + (size_t)g * 64 + tx * 8;
                *(float4*)p = make_float4(acc[i][0], acc[i][1], acc[i][2], acc[i][3]);
                *(float4*)(p + 4) = make_float4(acc[i][4], acc[i][5], acc[i][6], acc[i][7]);
            }
        }
    } else {
        int oc = (tx - 8) * 8;
        float4 b0 = *(const float4*)(b + oc);
        float4 b1v = *(const float4*)(b + oc + 4);
        const float bv[8] = {b0.x, b0.y, b0.z, b0.w, b1v.x, b1v.y, b1v.z, b1v.w};
#pragma unroll
        for (int i = 0; i < 4; ++i) {
            int g = nbase + ty * 4 + i;
            if (g < N) {
                float* p = outp + (size_t)g * 64 + oc;
                *(float4*)p = make_float4(acc[i][0] + bv[0], acc[i][1] + bv[1],
                                          acc[i][2] + bv[2], acc[i][3] + bv[3]);
                *(float4*)(p + 4) = make_float4(acc[i][4] + bv[4], acc[i][5] + bv[5],
                                                acc[i][6] + bv[6], acc[i][7] + bv[7]);
            }
        }
    }
}

extern "C" void kernel_launch(void* const* d_in, const int* in_sizes, int n_in,
                              void* d_out, int out_size, void* d_ws, size_t ws_size,
                              hipStream_t stream) {
    const float* x   = (const float*)d_in[0];
    const int*   ei  = (const int*)d_in[1];
    const float* W1l = (const float*)d_in[2];
    const float* W1r = (const float*)d_in[3];
    const float* b1  = (const float*)d_in[4];
    const float* W2l = (const float*)d_in[5];
    const float* W2r = (const float*)d_in[6];
    const float* b2  = (const float*)d_in[7];
    float* out = (float*)d_out;

    const int N = in_sizes[0] / 128;   // 50000
    const int E = in_sizes[1] / 2;     // 640000
    const int* srcv = ei;
    const int* dstv = ei + E;

    float* agg1 = (float*)d_ws;                  // N*128
    float* h    = agg1 + (size_t)N * 128;        // N*128
    float* hl   = h    + (size_t)N * 128;        // N*64
    float* deg  = hl   + (size_t)N * 64;         // N (deg -> inv_deg in place)

    hipMemsetAsync(agg1, 0, (size_t)N * 128 * sizeof(float), stream);
    hipMemsetAsync(deg, 0, (size_t)N * sizeof(float), stream);

    deg_kernel<<<(E + 255) / 256, 256, 0, stream>>>(dstv, deg, E);
    invdeg_kernel<<<(N + 255) / 256, 256, 0, stream>>>(deg, N);

    // layer 1 aggregation: agg1[d] += x[s]
    scatter_add_kernel<32><<<(int)(((size_t)E * 32 + 255) / 256), 256, 0, stream>>>(
        srcv, dstv, x, agg1, nullptr, E);

    int nb = (N + 63) / 64;
    gemm1_kernel<<<nb, 256, 0, stream>>>(agg1, x, deg, W1l, W1r, b1, h, N);
    gemm2_kernel<<<nb, 256, 0, stream>>>(h, W2l, W2r, b2, hl, out, N);

    // layer 2 aggregation: out[d] += inv[d] * hl[s]
    scatter_add_kernel<16><<<(int)(((size_t)E * 16 + 255) / 256), 256, 0, stream>>>(
        srcv, dstv, hl, out, deg, E);
}

// Round 2
// 254.659 us; speedup vs baseline: 6.9536x; 6.9536x over previous
//
#include <hip/hip_runtime.h>

// GraphSAGE 2-layer fp32. Atomic scatter replaced by on-device CSR build + gather.
// out = SAGE2( relu( SAGE1(x) ) ), SAGE(x) = meanagg(x)@W_l + x@W_r + b
// Layer 2 uses linearity: meanagg(h)@W2_l == meanagg(h@W2_l) -> gather 64 floats/edge.

// ---------- CSR build ----------
__global__ void deg_int_kernel(const int* __restrict__ dst, int* __restrict__ degi, int E) {
    int e = blockIdx.x * blockDim.x + threadIdx.x;
    if (e < E) atomicAdd(&degi[dst[e]], 1);
}

// in-place block-inclusive scan (256/block); degi -> incl, block totals -> bsum
__global__ __launch_bounds__(256) void scan_pass1(int* __restrict__ deg, int* __restrict__ bsum, int N) {
    int tid = threadIdx.x;
    int i = blockIdx.x * 256 + tid;
    int v = (i < N) ? deg[i] : 0;
    int lane = tid & 63, wid = tid >> 6;
    int s = v;
#pragma unroll
    for (int off = 1; off < 64; off <<= 1) { int t = __shfl_up(s, off); if (lane >= off) s += t; }
    __shared__ int ws[4], wo[4];
    if (lane == 63) ws[wid] = s;
    __syncthreads();
    if (tid == 0) { int a = 0; for (int w = 0; w < 4; ++w) { wo[w] = a; a += ws[w]; } bsum[blockIdx.x] = a; }
    __syncthreads();
    s += wo[wid];
    if (i < N) deg[i] = s;   // in place: each element read only by its own thread before writes
}

__global__ __launch_bounds__(256) void scan_pass2(int* __restrict__ bsum, int* __restrict__ boff,
                                                  int nblk, int* __restrict__ rp) {
    int tid = threadIdx.x;
    int v = (tid < nblk) ? bsum[tid] : 0;
    int lane = tid & 63, wid = tid >> 6;
    int s = v;
#pragma unroll
    for (int off = 1; off < 64; off <<= 1) { int t = __shfl_up(s, off); if (lane >= off) s += t; }
    __shared__ int ws[4], wo[4];
    if (lane == 63) ws[wid] = s;
    __syncthreads();
    if (tid == 0) { int a = 0; for (int w = 0; w < 4; ++w) { wo[w] = a; a += ws[w]; } }
    __syncthreads();
    s += wo[wid];
    if (tid < nblk) boff[tid] = s - v;   // exclusive
    if (tid == 0) rp[0] = 0;
}

__global__ __launch_bounds__(256) void scan_pass3(const int* __restrict__ incl, const int* __restrict__ boff,
                                                  int* __restrict__ rp, int N) {
    int i = blockIdx.x * 256 + threadIdx.x;
    if (i < N) rp[i + 1] = boff[blockIdx.x] + incl[i];
}

// cursor = rp[i]; inv = 1/max(deg,1)
__global__ void prep_kernel(const int* __restrict__ rp, int* __restrict__ cursor,
                            float* __restrict__ inv, int N) {
    int i = blockIdx.x * blockDim.x + threadIdx.x;
    if (i < N) {
        int b = rp[i], e = rp[i + 1];
        cursor[i] = b;
        inv[i] = 1.0f / fmaxf((float)(e - b), 1.0f);
    }
}

__global__ void build_kernel(const int* __restrict__ src, const int* __restrict__ dst,
                             int* __restrict__ cursor, int* __restrict__ csr, int E) {
    int e = blockIdx.x * blockDim.x + threadIdx.x;
    if (e < E) {
        int p = atomicAdd(&cursor[dst[e]], 1);
        csr[p] = src[e];
    }
}

// ---------- gather aggregation ----------
// one wave per node; 128 floats -> float2 per lane
__global__ __launch_bounds__(256) void agg128_kernel(const int* __restrict__ rp, const int* __restrict__ ci,
                                                     const float* __restrict__ x, float* __restrict__ agg, int N) {
    int node = (blockIdx.x * 256 + threadIdx.x) >> 6;
    int lane = threadIdx.x & 63;
    if (node >= N) return;
    int beg = rp[node], end = rp[node + 1];
    const float2* xp = (const float2*)x;
    float2 acc = make_float2(0.f, 0.f);
    for (int base = beg; base < end; base += 64) {
        int idx = base + lane;
        int sv = (idx < end) ? ci[idx] : 0;
        int cnt = min(64, end - base);
        int j = 0;
        for (; j + 4 <= cnt; j += 4) {
            int s0 = __shfl(sv, j), s1 = __shfl(sv, j + 1), s2 = __shfl(sv, j + 2), s3 = __shfl(sv, j + 3);
            float2 v0 = xp[(size_t)s0 * 64 + lane];
            float2 v1 = xp[(size_t)s1 * 64 + lane];
            float2 v2 = xp[(size_t)s2 * 64 + lane];
            float2 v3 = xp[(size_t)s3 * 64 + lane];
            acc.x += v0.x + v1.x + v2.x + v3.x;
            acc.y += v0.y + v1.y + v2.y + v3.y;
        }
        for (; j < cnt; ++j) {
            int s = __shfl(sv, j);
            float2 v = xp[(size_t)s * 64 + lane];
            acc.x += v.x; acc.y += v.y;
        }
    }
    ((float2*)agg)[(size_t)node * 64 + lane] = acc;
}

// one wave per node; 64 floats -> 1 per lane; out[n] += inv[n]*sum(hl[src])
__global__ __launch_bounds__(256) void agg64_kernel(const int* __restrict__ rp, const int* __restrict__ ci,
                                                    const float* __restrict__ hl, const float* __restrict__ inv,
                                                    float* __restrict__ out, int N) {
    int node = (blockIdx.x * 256 + threadIdx.x) >> 6;
    int lane = threadIdx.x & 63;
    if (node >= N) return;
    int beg = rp[node], end = rp[node + 1];
    float acc = 0.f;
    for (int base = beg; base < end; base += 64) {
        int idx = base + lane;
        int sv = (idx < end) ? ci[idx] : 0;
        int cnt = min(64, end - base);
        int j = 0;
        for (; j + 4 <= cnt; j += 4) {
            int s0 = __shfl(sv, j), s1 = __shfl(sv, j + 1), s2 = __shfl(sv, j + 2), s3 = __shfl(sv, j + 3);
            acc += hl[(size_t)s0 * 64 + lane] + hl[(size_t)s1 * 64 + lane]
                 + hl[(size_t)s2 * 64 + lane] + hl[(size_t)s3 * 64 + lane];
        }
        for (; j < cnt; ++j) {
            int s = __shfl(sv, j);
            acc += hl[(size_t)s * 64 + lane];
        }
    }
    size_t o = (size_t)node * 64 + lane;
    out[o] += inv[node] * acc;
}

// ---------- GEMMs (unchanged structure) ----------
// Layer 1: h[n][o] = relu( (inv[n]*agg[n]) @ W1l + x[n] @ W1r + b1 )
__global__ __launch_bounds__(256) void gemm1_kernel(
    const float* __restrict__ agg, const float* __restrict__ x,
    const float* __restrict__ inv,
    const float* __restrict__ Wl, const float* __restrict__ Wr,
    const float* __restrict__ b, float* __restrict__ h, int N)
{
    __shared__ float At[64][68];
    __shared__ float Wt[64][132];
    const int tid = threadIdx.x;
    const int tx = tid & 15;
    const int ty = tid >> 4;
    const int nbase = blockIdx.x * 64;

    float acc[4][8];
#pragma unroll
    for (int i = 0; i < 4; ++i)
#pragma unroll
        for (int j = 0; j < 8; ++j) acc[i][j] = 0.f;

    for (int kt = 0; kt < 4; ++kt) {
        const float* Asrc = (kt < 2) ? agg : x;
        const int kcol = (kt & 1) * 64;
        const bool scaled = (kt < 2);
#pragma unroll
        for (int i = 0; i < 4; ++i) {
            int f = tid + i * 256;
            int row = f >> 4, c4 = f & 15;
            int g = nbase + row;
            float4 v = make_float4(0.f, 0.f, 0.f, 0.f);
            if (g < N) {
                v = *(const float4*)(Asrc + (size_t)g * 128 + kcol + c4 * 4);
                if (scaled) { float s = inv[g]; v.x *= s; v.y *= s; v.z *= s; v.w *= s; }
            }
            *(float4*)&At[row][c4 * 4] = v;
        }
#pragma unroll
        for (int i = 0; i < 8; ++i) {
            int f = tid + i * 256;
            int row = f >> 5, c4 = f & 31;
            int gk = kt * 64 + row;
            const float* Wsrc = (gk < 128) ? Wl : Wr;
            int wr = gk & 127;
            float4 v = *(const float4*)(Wsrc + wr * 128 + c4 * 4);
            *(float4*)&Wt[row][c4 * 4] = v;
        }
        __syncthreads();
#pragma unroll 8
        for (int kk = 0; kk < 64; ++kk) {
            float a0 = At[ty * 4 + 0][kk];
            float a1 = At[ty * 4 + 1][kk];
            float a2 = At[ty * 4 + 2][kk];
            float a3 = At[ty * 4 + 3][kk];
            float4 w0 = *(const float4*)&Wt[kk][tx * 8];
            float4 w1 = *(const float4*)&Wt[kk][tx * 8 + 4];
            const float wv[8] = {w0.x, w0.y, w0.z, w0.w, w1.x, w1.y, w1.z, w1.w};
#pragma unroll
            for (int j = 0; j < 8; ++j) {
                acc[0][j] += a0 * wv[j];
                acc[1][j] += a1 * wv[j];
                acc[2][j] += a2 * wv[j];
                acc[3][j] += a3 * wv[j];
            }
        }
        __syncthreads();
    }
    float4 b0 = *(const float4*)(b + tx * 8);
    float4 b1v = *(const float4*)(b + tx * 8 + 4);
    const float bv[8] = {b0.x, b0.y, b0.z, b0.w, b1v.x, b1v.y, b1v.z, b1v.w};
#pragma unroll
    for (int i = 0; i < 4; ++i) {
        int g = nbase + ty * 4 + i;
        if (g < N) {
            float o[8];
#pragma unroll
            for (int j = 0; j < 8; ++j) o[j] = fmaxf(acc[i][j] + bv[j], 0.f);
            float* p = h + (size_t)g * 128 + tx * 8;
            *(float4*)p = make_float4(o[0], o[1], o[2], o[3]);
            *(float4*)(p + 4) = make_float4(o[4], o[5], o[6], o[7]);
        }
    }
}

// Layer 2: cols 0..63 -> hl = h@W2l; cols 64..127 -> out = h@W2r + b2
__global__ __launch_bounds__(256) void gemm2_kernel(
    const float* __restrict__ hin,
    const float* __restrict__ Wl, const float* __restrict__ Wr,
    const float* __restrict__ b, float* __restrict__ hl,
    float* __restrict__ outp, int N)
{
    __shared__ float At[64][68];
    __shared__ float Wt[64][132];
    const int tid = threadIdx.x;
    const int tx = tid & 15;
    const int ty = tid >> 4;
    const int nbase = blockIdx.x * 64;

    float acc[4][8];
#pragma unroll
    for (int i = 0; i < 4; ++i)
#pragma unroll
        for (int j = 0; j < 8; ++j) acc[i][j] = 0.f;

    for (int kt = 0; kt < 2; ++kt) {
        const int kcol = kt * 64;
#pragma unroll
        for (int i = 0; i < 4; ++i) {
            int f = tid + i * 256;
            int row = f >> 4, c4 = f & 15;
            int g = nbase + row;
            float4 v = make_float4(0.f, 0.f, 0.f, 0.f);
            if (g < N) v = *(const float4*)(hin + (size_t)g * 128 + kcol + c4 * 4);
            *(float4*)&At[row][c4 * 4] = v;
        }
#pragma unroll
        for (int i = 0; i < 8; ++i) {
            int f = tid + i * 256;
            int row = f >> 5, c4 = f & 31;
            int gk = kt * 64 + row;
            float4 v;
            if (c4 < 16) v = *(const float4*)(Wl + gk * 64 + c4 * 4);
            else         v = *(const float4*)(Wr + gk * 64 + (c4 - 16) * 4);
            *(float4*)&Wt[row][c4 * 4] = v;
        }
        __syncthreads();
#pragma unroll 8
        for (int kk = 0; kk < 64; ++kk) {
            float a0 = At[ty * 4 + 0][kk];
            float a1 = At[ty * 4 + 1][kk];
            float a2 = At[ty * 4 + 2][kk];
            float a3 = At[ty * 4 + 3][kk];
            float4 w0 = *(const float4*)&Wt[kk][tx * 8];
            float4 w1 = *(const float4*)&Wt[kk][tx * 8 + 4];
            const float wv[8] = {w0.x, w0.y, w0.z, w0.w, w1.x, w1.y, w1.z, w1.w};
#pragma unroll
            for (int j = 0; j < 8; ++j) {
                acc[0][j] += a0 * wv[j];
                acc[1][j] += a1 * wv[j];
                acc[2][j] += a2 * wv[j];
                acc[3][j] += a3 * wv[j];
            }
        }
        __syncthreads();
    }
    if (tx < 8) {
#pragma unroll
        for (int i = 0; i < 4; ++i) {
            int g = nbase + ty * 4 + i;
            if (g < N) {
                float* p = hl + (size_t)g * 64 + tx * 8;
                *(float4*)p = make_float4(acc[i][0], acc[i][1], acc[i][2], acc[i][3]);
                *(float4*)(p + 4) = make_float4(acc[i][4], acc[i][5], acc[i][6], acc[i][7]);
            }
        }
    } else {
        int oc = (tx - 8) * 8;
        float4 b0 = *(const float4*)(b + oc);
        float4 b1v = *(const float4*)(b + oc + 4);
        const float bv[8] = {b0.x, b0.y, b0.z, b0.w, b1v.x, b1v.y, b1v.z, b1v.w};
#pragma unroll
        for (int i = 0; i < 4; ++i) {
            int g = nbase + ty * 4 + i;
            if (g < N) {
                float* p = outp + (size_t)g * 64 + oc;
                *(float4*)p = make_float4(acc[i][0] + bv[0], acc[i][1] + bv[1],
                                          acc[i][2] + bv[2], acc[i][3] + bv[3]);
                *(float4*)(p + 4) = make_float4(acc[i][4] + bv[4], acc[i][5] + bv[5],
                                                acc[i][6] + bv[6], acc[i][7] + bv[7]);
            }
        }
    }
}

extern "C" void kernel_launch(void* const* d_in, const int* in_sizes, int n_in,
                              void* d_out, int out_size, void* d_ws, size_t ws_size,
                              hipStream_t stream) {
    const float* x   = (const float*)d_in[0];
    const int*   ei  = (const int*)d_in[1];
    const float* W1l = (const float*)d_in[2];
    const float* W1r = (const float*)d_in[3];
    const float* b1  = (const float*)d_in[4];
    const float* W2l = (const float*)d_in[5];
    const float* W2r = (const float*)d_in[6];
    const float* b2  = (const float*)d_in[7];
    float* out = (float*)d_out;

    const int N = in_sizes[0] / 128;   // 50000
    const int E = in_sizes[1] / 2;     // 640000
    const int* srcv = ei;
    const int* dstv = ei + E;

    // workspace layout (hl aliases agg1: agg1 is dead after gemm1)
    float* agg1 = (float*)d_ws;                       // N*128 floats
    float* hl   = agg1;                               // N*64 floats (alias)
    float* h    = agg1 + (size_t)N * 128;             // N*128 floats
    float* inv  = h + (size_t)N * 128;                // N floats
    int*   rp   = (int*)(inv + N);                    // N+1 ints
    int*   cur  = rp + (N + 1);                       // N ints
    int*   degi = cur + N;                            // N ints (also scan incl, in place)
    int*   csr  = degi + N;                           // E ints
    int*   bsum = csr + E;                            // 256 ints
    int*   boff = bsum + 256;                         // 256 ints

    const int nsblk = (N + 255) / 256;                // 196

    hipMemsetAsync(degi, 0, (size_t)N * sizeof(int), stream);
    deg_int_kernel<<<(E + 255) / 256, 256, 0, stream>>>(dstv, degi, E);
    scan_pass1<<<nsblk, 256, 0, stream>>>(degi, bsum, N);
    scan_pass2<<<1, 256, 0, stream>>>(bsum, boff, nsblk, rp);
    scan_pass3<<<nsblk, 256, 0, stream>>>(degi, boff, rp, N);
    prep_kernel<<<nsblk, 256, 0, stream>>>(rp, cur, inv, N);
    build_kernel<<<(E + 255) / 256, 256, 0, stream>>>(srcv, dstv, cur, csr, E);

    // layer 1
    int aggblk = (N * 64 + 255) / 256;                // one wave per node
    agg128_kernel<<<aggblk, 256, 0, stream>>>(rp, csr, x, agg1, N);
    int nb = (N + 63) / 64;
    gemm1_kernel<<<nb, 256, 0, stream>>>(agg1, x, inv, W1l, W1r, b1, h, N);

    // layer 2
    gemm2_kernel<<<nb, 256, 0, stream>>>(h, W2l, W2r, b2, hl, out, N);
    agg64_kernel<<<aggblk, 256, 0, stream>>>(rp, csr, hl, inv, out, N);
}

// Round 3
// 166.491 us; speedup vs baseline: 10.6361x; 1.5296x over previous
//
#include <hip/hip_runtime.h>
#include <hip/hip_fp16.h>

// GraphSAGE 2-layer. CSR build + wave-gather aggregation (no float atomics),
// fp16 activations/weights with MFMA f32_16x16x32_f16 GEMMs (fp32 accum).
// out = SAGE2( relu( SAGE1(x) ) ), SAGE(x) = meanagg(x)@W_l + x@W_r + b
// Layer 2 linearity: meanagg(h)@W2_l == meanagg(h@W2_l) -> gather 64 vals/edge.

typedef _Float16 half8 __attribute__((ext_vector_type(8)));
typedef float floatx4 __attribute__((ext_vector_type(4)));

// ---------- CSR build ----------
__global__ void deg_int_kernel(const int* __restrict__ dst, int* __restrict__ degi, int E) {
    int e = blockIdx.x * blockDim.x + threadIdx.x;
    if (e < E) atomicAdd(&degi[dst[e]], 1);
}

__global__ __launch_bounds__(256) void scan_pass1(int* __restrict__ deg, int* __restrict__ bsum, int N) {
    int tid = threadIdx.x;
    int i = blockIdx.x * 256 + tid;
    int v = (i < N) ? deg[i] : 0;
    int lane = tid & 63, wid = tid >> 6;
    int s = v;
#pragma unroll
    for (int off = 1; off < 64; off <<= 1) { int t = __shfl_up(s, off); if (lane >= off) s += t; }
    __shared__ int ws[4], wo[4];
    if (lane == 63) ws[wid] = s;
    __syncthreads();
    if (tid == 0) { int a = 0; for (int w = 0; w < 4; ++w) { wo[w] = a; a += ws[w]; } bsum[blockIdx.x] = a; }
    __syncthreads();
    s += wo[wid];
    if (i < N) deg[i] = s;
}

__global__ __launch_bounds__(256) void scan_pass2(int* __restrict__ bsum, int* __restrict__ boff,
                                                  int nblk, int* __restrict__ rp) {
    int tid = threadIdx.x;
    int v = (tid < nblk) ? bsum[tid] : 0;
    int lane = tid & 63, wid = tid >> 6;
    int s = v;
#pragma unroll
    for (int off = 1; off < 64; off <<= 1) { int t = __shfl_up(s, off); if (lane >= off) s += t; }
    __shared__ int ws[4], wo[4];
    if (lane == 63) ws[wid] = s;
    __syncthreads();
    if (tid == 0) { int a = 0; for (int w = 0; w < 4; ++w) { wo[w] = a; a += ws[w]; } }
    __syncthreads();
    s += wo[wid];
    if (tid < nblk) boff[tid] = s - v;
    if (tid == 0) rp[0] = 0;
}

__global__ __launch_bounds__(256) void scan_pass3(const int* __restrict__ incl, const int* __restrict__ boff,
                                                  int* __restrict__ rp, int N) {
    int i = blockIdx.x * 256 + threadIdx.x;
    if (i < N) rp[i + 1] = boff[blockIdx.x] + incl[i];
}

__global__ void prep_kernel(const int* __restrict__ rp, int* __restrict__ cursor,
                            float* __restrict__ inv, int N) {
    int i = blockIdx.x * blockDim.x + threadIdx.x;
    if (i < N) {
        int b = rp[i], e = rp[i + 1];
        cursor[i] = b;
        inv[i] = 1.0f / fmaxf((float)(e - b), 1.0f);
    }
}

__global__ void build_kernel(const int* __restrict__ src, const int* __restrict__ dst,
                             int* __restrict__ cursor, int* __restrict__ csr, int E) {
    int e = blockIdx.x * blockDim.x + threadIdx.x;
    if (e < E) {
        int p = atomicAdd(&cursor[dst[e]], 1);
        csr[p] = src[e];
    }
}

// ---------- fp16 conversion / weight packing ----------
// Ah row layout (256 halves): [0:128] = inv*meanagg (written by agg128h), [128:256] = fp16(x)
__global__ void convert_x_kernel(const float* __restrict__ x, _Float16* __restrict__ Ah, int N) {
    int i = blockIdx.x * blockDim.x + threadIdx.x;   // over N*64 float2
    if (i >= N * 64) return;
    int row = i >> 6, c = i & 63;
    float2 v = ((const float2*)x)[(size_t)row * 64 + c];
    _Float16* p = Ah + (size_t)row * 256 + 128 + c * 2;
    p[0] = (_Float16)v.x;
    p[1] = (_Float16)v.y;
}

// Pack B^T frag-contiguous: Bp[((kt*8+nrep)*64+lane)*8 + j] = B[k][col],
// k = kt*32 + (lane>>4)*8 + j, col = nrep*16 + (lane&15).
// GEMM1: B = [W1l; W1r] (256x128).  KT=8
__global__ void pack1_kernel(const float* __restrict__ Wl, const float* __restrict__ Wr,
                             _Float16* __restrict__ Bp) {
    int t = blockIdx.x * blockDim.x + threadIdx.x;   // 32768
    if (t >= 8 * 8 * 64 * 8) return;
    int j = t & 7, lane = (t >> 3) & 63, nrep = (t >> 9) & 7, kt = t >> 12;
    int k = kt * 32 + ((lane >> 4) * 8) + j;
    int col = nrep * 16 + (lane & 15);
    float v = (k < 128) ? Wl[k * 128 + col] : Wr[(k - 128) * 128 + col];
    Bp[t] = (_Float16)v;
}

// GEMM2: B = [W2l | W2r] (128x128, first 64 cols W2l, last 64 W2r).  KT=4
__global__ void pack2_kernel(const float* __restrict__ Wl, const float* __restrict__ Wr,
                             _Float16* __restrict__ Bp) {
    int t = blockIdx.x * blockDim.x + threadIdx.x;   // 16384
    if (t >= 4 * 8 * 64 * 8) return;
    int j = t & 7, lane = (t >> 3) & 63, nrep = (t >> 9) & 7, kt = t >> 12;
    int k = kt * 32 + ((lane >> 4) * 8) + j;
    int col = nrep * 16 + (lane & 15);
    float v = (col < 64) ? Wl[k * 64 + col] : Wr[k * 64 + (col - 64)];
    Bp[t] = (_Float16)v;
}

// ---------- gather aggregation (fp16 payload, fp32 accum) ----------
// one wave per node: lane holds half2 (cols 2*lane, 2*lane+1) of the x-part of Ah
__global__ __launch_bounds__(256) void agg128h_kernel(const int* __restrict__ rp, const int* __restrict__ ci,
                                                      _Float16* __restrict__ Ah,
                                                      const float* __restrict__ inv, int N) {
    int node = (blockIdx.x * 256 + threadIdx.x) >> 6;
    int lane = threadIdx.x & 63;
    if (node >= N) return;
    int beg = rp[node], end = rp[node + 1];
    const uint* xu = (const uint*)Ah;   // half2 units; row = 128 units, x-part at +64
    float2 acc = make_float2(0.f, 0.f);
    for (int base = beg; base < end; base += 64) {
        int idx = base + lane;
        int sv = (idx < end) ? ci[idx] : 0;
        int cnt = min(64, end - base);
        int j = 0;
        for (; j + 4 <= cnt; j += 4) {
            int s0 = __shfl(sv, j), s1 = __shfl(sv, j + 1), s2 = __shfl(sv, j + 2), s3 = __shfl(sv, j + 3);
            uint u0 = xu[(size_t)s0 * 128 + 64 + lane];
            uint u1 = xu[(size_t)s1 * 128 + 64 + lane];
            uint u2 = xu[(size_t)s2 * 128 + 64 + lane];
            uint u3 = xu[(size_t)s3 * 128 + 64 + lane];
            float2 f0 = __half22float2(*(const __half2*)&u0);
            float2 f1 = __half22float2(*(const __half2*)&u1);
            float2 f2 = __half22float2(*(const __half2*)&u2);
            float2 f3 = __half22float2(*(const __half2*)&u3);
            acc.x += f0.x + f1.x + f2.x + f3.x;
            acc.y += f0.y + f1.y + f2.y + f3.y;
        }
        for (; j < cnt; ++j) {
            int s = __shfl(sv, j);
            uint u = xu[(size_t)s * 128 + 64 + lane];
            float2 f = __half22float2(*(const __half2*)&u);
            acc.x += f.x; acc.y += f.y;
        }
    }
    float iv = inv[node];
    __half2 o = __floats2half2_rn(acc.x * iv, acc.y * iv);
    ((uint*)Ah)[(size_t)node * 128 + lane] = *(const uint*)&o;
}

// half-wave (32 lanes) per node: lane holds half2 (cols 2*sl, 2*sl+1) of hl; out += inv*sum
__global__ __launch_bounds__(256) void agg64h_kernel(const int* __restrict__ rp, const int* __restrict__ ci,
                                                     const _Float16* __restrict__ hl,
                                                     const float* __restrict__ inv,
                                                     float* __restrict__ out, int N) {
    int node = (blockIdx.x * 256 + threadIdx.x) >> 5;
    int sl = threadIdx.x & 31;
    if (node >= N) return;
    int beg = rp[node], end = rp[node + 1];
    const uint* hu = (const uint*)hl;   // 32 half2 per row
    float2 acc = make_float2(0.f, 0.f);
    for (int base = beg; base < end; base += 32) {
        int idx = base + sl;
        int sv = (idx < end) ? ci[idx] : 0;
        int cnt = min(32, end - base);
        int j = 0;
        for (; j + 4 <= cnt; j += 4) {
            int s0 = __shfl(sv, j, 32), s1 = __shfl(sv, j + 1, 32);
            int s2 = __shfl(sv, j + 2, 32), s3 = __shfl(sv, j + 3, 32);
            uint u0 = hu[(size_t)s0 * 32 + sl];
            uint u1 = hu[(size_t)s1 * 32 + sl];
            uint u2 = hu[(size_t)s2 * 32 + sl];
            uint u3 = hu[(size_t)s3 * 32 + sl];
            float2 f0 = __half22float2(*(const __half2*)&u0);
            float2 f1 = __half22float2(*(const __half2*)&u1);
            float2 f2 = __half22float2(*(const __half2*)&u2);
            float2 f3 = __half22float2(*(const __half2*)&u3);
            acc.x += f0.x + f1.x + f2.x + f3.x;
            acc.y += f0.y + f1.y + f2.y + f3.y;
        }
        for (; j < cnt; ++j) {
            int s = __shfl(sv, j, 32);
            uint u = hu[(size_t)s * 32 + sl];
            float2 f = __half22float2(*(const __half2*)&u);
            acc.x += f.x; acc.y += f.y;
        }
    }
    float iv = inv[node];
    float2* op = (float2*)(out + (size_t)node * 64 + sl * 2);
    float2 cur = *op;
    cur.x += iv * acc.x;
    cur.y += iv * acc.y;
    *op = cur;
}

// ---------- MFMA GEMMs ----------
// gemm1: h = relu( Ah(50000x256 fp16) @ Bp1(256x128) + b1 ) -> hh fp16
// block 256 = 4 waves; wave does 32 rows x 128 cols; BM=128/block
__global__ __launch_bounds__(256) void gemm1_mfma(const _Float16* __restrict__ Ah,
                                                  const _Float16* __restrict__ Bp,
                                                  const float* __restrict__ b1,
                                                  _Float16* __restrict__ hh, int N) {
    int wid = threadIdx.x >> 6, lane = threadIdx.x & 63;
    int r = lane & 15, q = lane >> 4;
    int rowbase = blockIdx.x * 128 + wid * 32;
    size_t ra = (size_t)min(rowbase + r, N - 1);
    size_t rb = (size_t)min(rowbase + 16 + r, N - 1);
    const half8* B8 = (const half8*)Bp;

    floatx4 acc[2][8];
#pragma unroll
    for (int m = 0; m < 2; ++m)
#pragma unroll
        for (int n = 0; n < 8; ++n) acc[m][n] = (floatx4){0.f, 0.f, 0.f, 0.f};

#pragma unroll
    for (int kt = 0; kt < 8; ++kt) {
        int k0 = kt * 32 + q * 8;
        half8 a0 = *(const half8*)(Ah + ra * 256 + k0);
        half8 a1 = *(const half8*)(Ah + rb * 256 + k0);
#pragma unroll
        for (int n = 0; n < 8; ++n) {
            half8 bf = B8[(kt * 8 + n) * 64 + lane];
            acc[0][n] = __builtin_amdgcn_mfma_f32_16x16x32_f16(a0, bf, acc[0][n], 0, 0, 0);
            acc[1][n] = __builtin_amdgcn_mfma_f32_16x16x32_f16(a1, bf, acc[1][n], 0, 0, 0);
        }
    }
    float bias[8];
#pragma unroll
    for (int n = 0; n < 8; ++n) bias[n] = b1[n * 16 + r];
    // C/D: col = n*16 + (lane&15), row = m*16 + q*4 + reg
#pragma unroll
    for (int m = 0; m < 2; ++m)
#pragma unroll
        for (int reg = 0; reg < 4; ++reg) {
            int row = rowbase + m * 16 + q * 4 + reg;
            if (row < N) {
                _Float16* p = hh + (size_t)row * 128 + r;
#pragma unroll
                for (int n = 0; n < 8; ++n)
                    p[n * 16] = (_Float16)fmaxf(acc[m][n][reg] + bias[n], 0.f);
            }
        }
}

// gemm2: hh(50000x128 fp16) @ Bp2(128x128). cols 0..63 -> hl fp16; cols 64..127 -> out fp32 (+b2)
__global__ __launch_bounds__(256) void gemm2_mfma(const _Float16* __restrict__ hh,
                                                  const _Float16* __restrict__ Bp,
                                                  const float* __restrict__ b2,
                                                  _Float16* __restrict__ hl,
                                                  float* __restrict__ outp, int N) {
    int wid = threadIdx.x >> 6, lane = threadIdx.x & 63;
    int r = lane & 15, q = lane >> 4;
    int rowbase = blockIdx.x * 128 + wid * 32;
    size_t ra = (size_t)min(rowbase + r, N - 1);
    size_t rb = (size_t)min(rowbase + 16 + r, N - 1);
    const half8* B8 = (const half8*)Bp;

    floatx4 acc[2][8];
#pragma unroll
    for (int m = 0; m < 2; ++m)
#pragma unroll
        for (int n = 0; n < 8; ++n) acc[m][n] = (floatx4){0.f, 0.f, 0.f, 0.f};

#pragma unroll
    for (int kt = 0; kt < 4; ++kt) {
        int k0 = kt * 32 + q * 8;
        half8 a0 = *(const half8*)(hh + ra * 128 + k0);
        half8 a1 = *(const half8*)(hh + rb * 128 + k0);
#pragma unroll
        for (int n = 0; n < 8; ++n) {
            half8 bf = B8[(kt * 8 + n) * 64 + lane];
            acc[0][n] = __builtin_amdgcn_mfma_f32_16x16x32_f16(a0, bf, acc[0][n], 0, 0, 0);
            acc[1][n] = __builtin_amdgcn_mfma_f32_16x16x32_f16(a1, bf, acc[1][n], 0, 0, 0);
        }
    }
    float bias[4];
#pragma unroll
    for (int n = 0; n < 4; ++n) bias[n] = b2[n * 16 + r];
#pragma unroll
    for (int m = 0; m < 2; ++m)
#pragma unroll
        for (int reg = 0; reg < 4; ++reg) {
            int row = rowbase + m * 16 + q * 4 + reg;
            if (row < N) {
                _Float16* ph = hl + (size_t)row * 64 + r;
                float* po = outp + (size_t)row * 64 + r;
#pragma unroll
                for (int n = 0; n < 4; ++n)
                    ph[n * 16] = (_Float16)acc[m][n][reg];
#pragma unroll
                for (int n = 0; n < 4; ++n)
                    po[n * 16] = acc[m][n + 4][reg] + bias[n];
            }
        }
}

extern "C" void kernel_launch(void* const* d_in, const int* in_sizes, int n_in,
                              void* d_out, int out_size, void* d_ws, size_t ws_size,
                              hipStream_t stream) {
    const float* x   = (const float*)d_in[0];
    const int*   ei  = (const int*)d_in[1];
    const float* W1l = (const float*)d_in[2];
    const float* W1r = (const float*)d_in[3];
    const float* b1  = (const float*)d_in[4];
    const float* W2l = (const float*)d_in[5];
    const float* W2r = (const float*)d_in[6];
    const float* b2  = (const float*)d_in[7];
    float* out = (float*)d_out;

    const int N = in_sizes[0] / 128;   // 50000
    const int E = in_sizes[1] / 2;     // 640000
    const int* srcv = ei;
    const int* dstv = ei + E;

    // workspace layout
    _Float16* Ah  = (_Float16*)d_ws;                      // N*256 halves
    _Float16* hh  = Ah + (size_t)N * 256;                 // N*128 halves
    _Float16* hl  = hh + (size_t)N * 128;                 // N*64 halves
    _Float16* Bp1 = hl + (size_t)N * 64;                  // 32768 halves
    _Float16* Bp2 = Bp1 + 32768;                          // 16384 halves
    float* inv  = (float*)(Bp2 + 16384);                  // N floats
    int*   rp   = (int*)(inv + N);                        // N+1
    int*   cur  = rp + (N + 1);                           // N
    int*   degi = cur + N;                                // N
    int*   csr  = degi + N;                               // E
    int*   bsum = csr + E;                                // 256
    int*   boff = bsum + 256;                             // 256

    const int nsblk = (N + 255) / 256;

    hipMemsetAsync(degi, 0, (size_t)N * sizeof(int), stream);
    deg_int_kernel<<<(E + 255) / 256, 256, 0, stream>>>(dstv, degi, E);
    scan_pass1<<<nsblk, 256, 0, stream>>>(degi, bsum, N);
    scan_pass2<<<1, 256, 0, stream>>>(bsum, boff, nsblk, rp);
    scan_pass3<<<nsblk, 256, 0, stream>>>(degi, boff, rp, N);
    prep_kernel<<<nsblk, 256, 0, stream>>>(rp, cur, inv, N);
    build_kernel<<<(E + 255) / 256, 256, 0, stream>>>(srcv, dstv, cur, csr, E);

    convert_x_kernel<<<(N * 64 + 255) / 256, 256, 0, stream>>>(x, Ah, N);
    pack1_kernel<<<128, 256, 0, stream>>>(W1l, W1r, Bp1);
    pack2_kernel<<<64, 256, 0, stream>>>(W2l, W2r, Bp2);

    // layer 1
    agg128h_kernel<<<(N * 64 + 255) / 256, 256, 0, stream>>>(rp, csr, Ah, inv, N);
    int nb = (N + 127) / 128;
    gemm1_mfma<<<nb, 256, 0, stream>>>(Ah, Bp1, b1, hh, N);

    // layer 2
    gemm2_mfma<<<nb, 256, 0, stream>>>(hh, Bp2, b2, hl, out, N);
    agg64h_kernel<<<(N * 32 + 255) / 256, 256, 0, stream>>>(rp, csr, hl, inv, out, N);
}